// Round 1
// baseline (520.791 us; speedup 1.0000x reference)
//
#include <hip/hip_runtime.h>
#include <math.h>

typedef __attribute__((ext_vector_type(4))) float f32x4;
typedef __bf16 bf16x8 __attribute__((ext_vector_type(8)));

#define LOG_2PI_F 1.8378770664093453f

__device__ static inline ushort f2bf(float f) {
    union { float f; unsigned u; } c; c.f = f;
    unsigned u = c.u;
    unsigned r = (u + 0x7FFFu + ((u >> 16) & 1u)) >> 16;
    return (ushort)r;
}
__device__ static inline float bf2f(ushort h) {
    union { unsigned u; float f; } c; c.u = ((unsigned)h) << 16;
    return c.f;
}

// ---------------- prep: fp32 -> bf16 straight convert (obs) ----------------
__global__ void cvt_bf16(const float* __restrict__ in, ushort* __restrict__ out, int n4) {
    int i = blockIdx.x * blockDim.x + threadIdx.x;
    if (i >= n4) return;
    float4 v = ((const float4*)in)[i];
    ushort4 o;
    o.x = f2bf(v.x); o.y = f2bf(v.y); o.z = f2bf(v.z); o.w = f2bf(v.w);
    ((ushort4*)out)[i] = o;
}

// ---------------- prep: fp32 [R][C] -> bf16 [C][R] transpose ----------------
__global__ void transpose_cvt(const float* __restrict__ in, ushort* __restrict__ out,
                              int R, int C) {
    __shared__ float tile[32][33];
    int c0 = blockIdx.x << 5, r0 = blockIdx.y << 5;
    for (int j = threadIdx.y; j < 32; j += 8) {
        int r = r0 + j, c = c0 + threadIdx.x;
        if (r < R && c < C) tile[j][threadIdx.x] = in[(size_t)r * C + c];
    }
    __syncthreads();
    for (int j = threadIdx.y; j < 32; j += 8) {
        int c = c0 + j, r = r0 + threadIdx.x;
        if (r < R && c < C) out[(size_t)c * R + r] = f2bf(tile[threadIdx.x][j]);
    }
}

// ---------------- GEMM: C[M][N] = relu(A[M][K] @ Bt[N][K]^T + bias (+ role row)) ----
// 128x128 tile, BK=32, 4 waves (2x2), each wave 64x64 via 4x4 16x16x32 MFMA frags.
// A, Bt bf16 row-major; staged to LDS with global_load_lds dwordx4 (linear layout).
__global__ __launch_bounds__(256) void gemm_bias_relu(
    const ushort* __restrict__ A, const ushort* __restrict__ Bt,
    const float* __restrict__ bias, ushort* __restrict__ C,
    int M, int N, int K,
    const int* __restrict__ role_ids, const float* __restrict__ rolerows) {
    __shared__ __align__(16) ushort lA[128 * 32];
    __shared__ __align__(16) ushort lB[128 * 32];

    const int nb = N >> 7;
    const int brow = blockIdx.x / nb;
    const int bcol = blockIdx.x % nb;
    const int tid = threadIdx.x;
    const int wid = tid >> 6;
    const int lane = tid & 63;
    const int wr = wid >> 1, wc = wid & 1;       // 2x2 wave grid
    const int fr = lane & 15;                     // fragment row/col
    const int fkByte = ((lane >> 4) << 3);        // k elem offset 0/8/16/24
    const int crow4 = (lane >> 4) << 2;           // C row group

    f32x4 acc[4][4];
#pragma unroll
    for (int i = 0; i < 4; i++)
#pragma unroll
        for (int j = 0; j < 4; j++) acc[i][j] = (f32x4){0.f, 0.f, 0.f, 0.f};

    // staging: chunk = wid*2 + j covers rows 16*chunk..+15 (1KB), lane covers 16B
    const int rchunk = lane >> 2;                 // row within 16-row chunk
    const int kchunk = (lane & 3) << 3;           // k elem offset within 32 (0,8,16,24)
    const int aRow = brow * 128 + (wid << 5) + rchunk;
    const int bRow = bcol * 128 + (wid << 5) + rchunk;

    const int nk = K >> 5;
    for (int kt = 0; kt < nk; ++kt) {
        const int k0 = kt << 5;
#pragma unroll
        for (int j = 0; j < 2; j++) {
            const ushort* gA = A + (size_t)(aRow + 16 * j) * K + k0 + kchunk;
            __builtin_amdgcn_global_load_lds(
                (const __attribute__((address_space(1))) void*)gA,
                (__attribute__((address_space(3))) void*)(&lA[(wid << 10) + (j << 9)]),
                16, 0, 0);
            const ushort* gB = Bt + (size_t)(bRow + 16 * j) * K + k0 + kchunk;
            __builtin_amdgcn_global_load_lds(
                (const __attribute__((address_space(1))) void*)gB,
                (__attribute__((address_space(3))) void*)(&lB[(wid << 10) + (j << 9)]),
                16, 0, 0);
        }
        __syncthreads();

        bf16x8 af[4], bfr[4];
#pragma unroll
        for (int m = 0; m < 4; m++)
            af[m] = *(const bf16x8*)&lA[((wr << 6) + (m << 4) + fr) * 32 + fkByte];
#pragma unroll
        for (int n = 0; n < 4; n++)
            bfr[n] = *(const bf16x8*)&lB[((wc << 6) + (n << 4) + fr) * 32 + fkByte];
#pragma unroll
        for (int m = 0; m < 4; m++)
#pragma unroll
            for (int n = 0; n < 4; n++)
                acc[m][n] = __builtin_amdgcn_mfma_f32_16x16x32_bf16(af[m], bfr[n], acc[m][n], 0, 0, 0);
        __syncthreads();
    }

    // epilogue: bias (+ per-role row for layer0), relu, bf16 store
#pragma unroll
    for (int m = 0; m < 4; m++) {
        const int rowb = brow * 128 + (wr << 6) + (m << 4) + crow4;
#pragma unroll
        for (int j = 0; j < 4; j++) {
            const int r = rowb + j;
            int roleb = -1;
            if (role_ids) {
                int rr = role_ids[r];
                roleb = (rr < 2) ? rr : -1;
            }
#pragma unroll
            for (int n = 0; n < 4; n++) {
                const int col = bcol * 128 + (wc << 6) + (n << 4) + fr;
                float v = acc[m][n][j] + bias[col];
                if (roleb >= 0) v += rolerows[(size_t)roleb * N + col];
                v = v > 0.f ? v : 0.f;
                C[(size_t)r * N + col] = f2bf(v);
            }
        }
    }
}

// ---------------- final: head2 + tanh + gaussian logprob, wave per token ----------------
__global__ __launch_bounds__(256) void head_final(
    const ushort* __restrict__ z,       // [T][1024] bf16: cols 0-511 role0 z, 512-1023 role1 z
    const float* __restrict__ actions,  // [T][8]
    const int* __restrict__ role_ids,   // [T]
    const ushort* __restrict__ hW2t,    // [2][8][512] bf16
    const float* __restrict__ hb2,      // [2][8]
    const float* __restrict__ log_stds, // [2][8]
    float* __restrict__ out, int T) {
    const int lane = threadIdx.x & 63;
    const int t = blockIdx.x * (blockDim.x >> 6) + (threadIdx.x >> 6);
    if (t >= T) return;
    const int r = role_ids[t];
    if (r >= 2) {
        if (lane == 0) out[t] = 0.f;
        return;
    }
    const ushort* zp = z + (size_t)t * 1024 + r * 512;
    uint4 zr = ((const uint4*)zp)[lane];  // 8 bf16 per lane
    unsigned zz[4] = {zr.x, zr.y, zr.z, zr.w};
    float zv[8];
#pragma unroll
    for (int i = 0; i < 4; i++) {
        zv[2 * i]     = bf2f((ushort)(zz[i] & 0xffffu));
        zv[2 * i + 1] = bf2f((ushort)(zz[i] >> 16));
    }
    float dk[8];
#pragma unroll
    for (int k = 0; k < 8; k++) {
        const ushort* wp = hW2t + r * 4096 + k * 512;
        uint4 wv = ((const uint4*)wp)[lane];
        unsigned ww[4] = {wv.x, wv.y, wv.z, wv.w};
        float s = 0.f;
#pragma unroll
        for (int i = 0; i < 4; i++) {
            s += zv[2 * i]     * bf2f((ushort)(ww[i] & 0xffffu));
            s += zv[2 * i + 1] * bf2f((ushort)(ww[i] >> 16));
        }
        dk[k] = s;
    }
#pragma unroll
    for (int off = 32; off >= 1; off >>= 1) {
#pragma unroll
        for (int k = 0; k < 8; k++) dk[k] += __shfl_xor(dk[k], off, 64);
    }
    if (lane == 0) {
        float lp = 0.f;
#pragma unroll
        for (int k = 0; k < 8; k++) {
            float mean = tanhf(dk[k] + hb2[r * 8 + k]);
            float ls = log_stds[r * 8 + k];
            float diff = (actions[(size_t)t * 8 + k] - mean) * expf(-ls);
            lp += -0.5f * diff * diff - ls - 0.5f * LOG_2PI_F;
        }
        out[t] = lp;
    }
}

extern "C" void kernel_launch(void* const* d_in, const int* in_sizes, int n_in,
                              void* d_out, int out_size, void* d_ws, size_t ws_size,
                              hipStream_t stream) {
    const float* obs      = (const float*)d_in[0];
    const int*   role_ids = (const int*)d_in[1];
    const float* actions  = (const float*)d_in[2];
    const float* W0       = (const float*)d_in[3];
    const float* b0       = (const float*)d_in[4];
    const float* W1       = (const float*)d_in[5];
    const float* b1       = (const float*)d_in[6];
    const float* W2       = (const float*)d_in[7];
    const float* b2       = (const float*)d_in[8];
    const float* hW1      = (const float*)d_in[9];
    const float* hb1      = (const float*)d_in[10];
    const float* hW2      = (const float*)d_in[11];
    const float* hb2      = (const float*)d_in[12];
    const float* log_stds = (const float*)d_in[13];
    float* out = (float*)d_out;

    const int T = 32768, H = 1024, OB = 128, H2 = 512;

    char* ws = (char*)d_ws;
    ushort* obsb = (ushort*)ws; ws += (size_t)T * OB * 2;       // 8 MB
    ushort* W0t  = (ushort*)ws; ws += (size_t)H * OB * 2;       // 256 KB
    ushort* W1t  = (ushort*)ws; ws += (size_t)H * H * 2;        // 2 MB
    ushort* W2t  = (ushort*)ws; ws += (size_t)H * H * 2;        // 2 MB
    ushort* hW1t = (ushort*)ws; ws += (size_t)H * H * 2;        // 2 MB (both roles stacked)
    ushort* hW2t = (ushort*)ws; ws += (size_t)2 * 8 * H2 * 2;   // 16 KB
    ushort* bufA = (ushort*)ws; ws += (size_t)T * H * 2;        // 64 MB (h0, then h2)
    ushort* bufB = (ushort*)ws;                                 // 64 MB (h1, then z)

    // prep
    cvt_bf16<<<(T * OB / 4 + 255) / 256, 256, 0, stream>>>(obs, obsb, T * OB / 4);
    dim3 tb(32, 8);
    transpose_cvt<<<dim3(32, 4),  tb, 0, stream>>>(W0, W0t, OB, H);   // only first 128 rows
    transpose_cvt<<<dim3(32, 32), tb, 0, stream>>>(W1, W1t, H, H);
    transpose_cvt<<<dim3(32, 32), tb, 0, stream>>>(W2, W2t, H, H);
    transpose_cvt<<<dim3(16, 32), tb, 0, stream>>>(hW1, hW1t, H, H2);
    transpose_cvt<<<dim3(16, 32), tb, 0, stream>>>(hW1 + (size_t)H * H2, hW1t + (size_t)H2 * H, H, H2);
    transpose_cvt<<<dim3(1, 16),  tb, 0, stream>>>(hW2, hW2t, H2, 8);
    transpose_cvt<<<dim3(1, 16),  tb, 0, stream>>>(hW2 + (size_t)H2 * 8, hW2t + (size_t)8 * H2, H2, 8);

    // body + head1 GEMMs (each M=32768, N=1024)
    const int grid = (T / 128) * (H / 128);  // 2048
    gemm_bias_relu<<<grid, 256, 0, stream>>>(obsb, W0t, b0, bufA, T, H, OB,
                                             role_ids, W0 + 128 * H);
    gemm_bias_relu<<<grid, 256, 0, stream>>>(bufA, W1t, b1, bufB, T, H, H, nullptr, nullptr);
    gemm_bias_relu<<<grid, 256, 0, stream>>>(bufB, W2t, b2, bufA, T, H, H, nullptr, nullptr);
    gemm_bias_relu<<<grid, 256, 0, stream>>>(bufA, hW1t, hb1, bufB, T, H, H, nullptr, nullptr);

    // head2 + logprob
    head_final<<<T / 4, 256, 0, stream>>>(bufB, actions, role_ids, hW2t, hb2, log_stds, out, T);
}